// Round 1
// 264.867 us; speedup vs baseline: 1.0274x; 1.0274x over previous
//
#include <hip/hip_runtime.h>

#define N_NODES 100000
#define K_EIG   256
#define C_CH    128
#define BN      320              // rows per split-K chunk
#define NITER   5                // BN/64
#define NCHUNK  313              // ceil(N_NODES / BN); 313*320 = 100160
#define PART_TILE (128*64)       // floats per partial tile (4*313 tiles * 32KB = 41 MB <= d_out)
#define G2_BLOCKS 782            // ceil(N_NODES / 128)

typedef __attribute__((ext_vector_type(8))) short  short8;
typedef __attribute__((ext_vector_type(4))) float  float4v;

// fp32 -> bf16 bits with round-to-nearest-even
__device__ __forceinline__ unsigned int bf16_bits(float f) {
  union { float f; unsigned int u; } v; v.f = f;
  unsigned int r = v.u + 0x7fffu + ((v.u >> 16) & 1u);
  return r >> 16;
}
__device__ __forceinline__ unsigned int pack2(float a, float b) {
  return bf16_bits(a) | (bf16_bits(b) << 16);
}

// ---------------------------------------------------------------------------
// GEMM1: split-K MFMA. Output 256x128 split into 4 tiles of 128k x 64c
// (blockIdx.y = kt*2+ctile), 313 chunks of 320 rows -> 1252 blocks (was 626).
// Per-block LDS 24.5KB + 48 prefetch VGPRs -> 4 blocks/CU co-resident
// (launch_bounds(256,4)); one nearly-full dispatch round. The extra evecs/x
// re-read is L3-resident (ev 102MB + x 51MB + partials 41MB < 256MB L3).
// LDS row strides 65/33 dwords keep staging writes and u16 fragment reads
// <=2 lanes/bank (free).
// ---------------------------------------------------------------------------
__global__ __launch_bounds__(256, 4) void gemm1_kernel(
    const float* __restrict__ x, const float* __restrict__ evecs,
    float* __restrict__ partial) {
  __shared__ unsigned int ev_t[64 * 65];   // 64 n-rows x 128 k (bf16), +1 dw pad
  __shared__ unsigned int x_t [64 * 33];   // 64 n-rows x  64 c (bf16), +1 dw pad

  const int tid   = threadIdx.x;
  const int chunk = blockIdx.x;            // 0..NCHUNK-1
  const int tp    = blockIdx.y;            // 0..3 : kt*2 + ctile
  const int kt    = tp >> 1;
  const int ctile = tp & 1;
  const int w  = tid >> 6;                 // wave 0..3 -> k rows [w*32, w*32+32)
  const int l  = tid & 63;
  const int q  = l >> 4;
  const int lc = l & 15;

  float4v acc[2][4];
#pragma unroll
  for (int a = 0; a < 2; a++)
#pragma unroll
    for (int b = 0; b < 4; b++) acc[a][b] = (float4v)0.0f;

  const int nl   = tid >> 2;               // 0..63 : row within 64-row tile
  const int part = tid & 3;                // 0..3

  float4v evr[8], xr[4];
  // prologue: load iter 0
  {
    const int n = chunk * BN + nl;
    const bool ok = (n < N_NODES);
    const float* evp = evecs + (size_t)n * K_EIG + kt * 128 + part * 32;
    const float* xp  = x     + (size_t)n * C_CH  + ctile * 64 + part * 16;
#pragma unroll
    for (int i = 0; i < 8; i++)
      evr[i] = ok ? *(const float4v*)(evp + i * 4) : (float4v)0.0f;
#pragma unroll
    for (int i = 0; i < 4; i++)
      xr[i]  = ok ? *(const float4v*)(xp  + i * 4) : (float4v)0.0f;
  }

  for (int ic = 0; ic < NITER; ic++) {
    // stage current registers into LDS (bf16)
#pragma unroll
    for (int i = 0; i < 8; i++) {
      const int d = nl * 65 + part * 16 + i * 2;
      ev_t[d]     = pack2(evr[i].x, evr[i].y);
      ev_t[d + 1] = pack2(evr[i].z, evr[i].w);
    }
#pragma unroll
    for (int i = 0; i < 4; i++) {
      const int d = nl * 33 + part * 8 + i * 2;
      x_t[d]      = pack2(xr[i].x, xr[i].y);
      x_t[d + 1]  = pack2(xr[i].z, xr[i].w);
    }
    __syncthreads();

    // issue next iteration's global loads now; they complete during compute
    if (ic + 1 < NITER) {
      const int n = chunk * BN + (ic + 1) * 64 + nl;
      const bool ok = (n < N_NODES);
      const float* evp = evecs + (size_t)n * K_EIG + kt * 128 + part * 32;
      const float* xp  = x     + (size_t)n * C_CH  + ctile * 64 + part * 16;
#pragma unroll
      for (int i = 0; i < 8; i++)
        evr[i] = ok ? *(const float4v*)(evp + i * 4) : (float4v)0.0f;
#pragma unroll
      for (int i = 0; i < 4; i++)
        xr[i]  = ok ? *(const float4v*)(xp  + i * 4) : (float4v)0.0f;
    }

    const unsigned short* evs = (const unsigned short*)ev_t;
    const unsigned short* xs  = (const unsigned short*)x_t;
#pragma unroll
    for (int ks = 0; ks < 2; ks++) {
      const int nb = ks * 32 + q * 8;
      short8 afrag[2];
#pragma unroll
      for (int mt = 0; mt < 2; mt++) {
        const int m = w * 32 + mt * 16 + lc;
        short8 a;
#pragma unroll
        for (int j = 0; j < 8; j++) a[j] = (short)evs[(nb + j) * 130 + m];
        afrag[mt] = a;
      }
#pragma unroll
      for (int ct = 0; ct < 4; ct++) {
        const int c = ct * 16 + lc;
        short8 b;
#pragma unroll
        for (int j = 0; j < 8; j++) b[j] = (short)xs[(nb + j) * 66 + c];
        acc[0][ct] = __builtin_amdgcn_mfma_f32_16x16x32_bf16(afrag[0], b, acc[0][ct], 0, 0, 0);
        acc[1][ct] = __builtin_amdgcn_mfma_f32_16x16x32_bf16(afrag[1], b, acc[1][ct], 0, 0, 0);
      }
    }
    __syncthreads();
  }

  // C/D layout: col = lane&15, row = (lane>>4)*4 + reg
  float* pb = partial + (size_t)(tp * NCHUNK + chunk) * PART_TILE;
#pragma unroll
  for (int mt = 0; mt < 2; mt++)
#pragma unroll
    for (int ct = 0; ct < 4; ct++)
#pragma unroll
      for (int r = 0; r < 4; r++) {
        const int m = w * 32 + mt * 16 + q * 4 + r;
        const int c = ct * 16 + lc;
        pb[m * 64 + c] = acc[mt][ct][r];
      }
}

// ---------------------------------------------------------------------------
// Reduce partials, apply exp(-lambda*t), emit bf16 s pre-shuffled into MFMA
// B-fragment order: idx = (((k/32)*8 + c/16)*64 + ((k%32)/8)*16 + (c%16))*8 + k%8
// Partial layout: partial[(tp*NCHUNK + chunk)*8192 + m*64 + cc],
//   k = (tp>>1)*128 + m, c = (tp&1)*64 + cc
// ---------------------------------------------------------------------------
__global__ __launch_bounds__(256) void reduce_kernel(
    const float* __restrict__ partial, const float* __restrict__ evals,
    const float* __restrict__ dt, unsigned short* __restrict__ s_frag) {
  __shared__ float red[256];
  const int t  = threadIdx.x;
  const int o  = blockIdx.x * 64 + (t & 63);   // 0..32767
  const int p  = t >> 6;
  const int tp = o >> 13;                      // 0..3
  const int e  = o & 8191;                     // elem within tile
  const float* base = partial + (size_t)tp * NCHUNK * PART_TILE + e;
  float a0 = 0.f, a1 = 0.f, a2 = 0.f, a3 = 0.f;
  int ch = p;
  for (; ch + 12 < NCHUNK; ch += 16) {
    a0 += base[(size_t)(ch     ) * PART_TILE];
    a1 += base[(size_t)(ch +  4) * PART_TILE];
    a2 += base[(size_t)(ch +  8) * PART_TILE];
    a3 += base[(size_t)(ch + 12) * PART_TILE];
  }
  for (; ch < NCHUNK; ch += 4) a0 += base[(size_t)ch * PART_TILE];
  red[t] = (a0 + a1) + (a2 + a3);
  __syncthreads();
  if (t < 64) {
    const float tot = red[t] + red[t + 64] + red[t + 128] + red[t + 192];
    const int oo = blockIdx.x * 64 + t;
    const int tp2 = oo >> 13;
    const int e2  = oo & 8191;
    const int k = (tp2 >> 1) * 128 + (e2 >> 6);
    const int c = (tp2 & 1) * 64 + (e2 & 63);
    const float tv   = fmaxf(dt[0], 1e-8f);
    const float coef = expf(-evals[k] * tv);
    const float v = tot * coef;
    const int idx = ((((k >> 5) * 8 + (c >> 4)) * 64) + ((k & 31) >> 3) * 16 + (c & 15)) * 8 + (k & 7);
    s_frag[idx] = (unsigned short)bf16_bits(v);
  }
}

// ---------------------------------------------------------------------------
// GEMM2: out[n][c] = sum_k evecs[n][k] * s[k][c]
// No LDS at all: B-fragments stream from the fragment-ordered 64KB s buffer
// (L2-resident, lane-contiguous 16B reads); A rows come straight from global
// with explicit ks+1 register prefetch.
// ---------------------------------------------------------------------------
__global__ __launch_bounds__(256, 3) void gemm2_kernel(
    const float* __restrict__ evecs, const unsigned short* __restrict__ s_frag,
    float* __restrict__ out) {
  const int tid = threadIdx.x;
  const int w  = tid >> 6, l = tid & 63, q = l >> 4, lc = l & 15;
  const int rowbase = blockIdx.x * 128 + w * 32;

  int n0 = rowbase + lc;        n0 = (n0 < N_NODES) ? n0 : (N_NODES - 1);
  int n1 = rowbase + 16 + lc;   n1 = (n1 < N_NODES) ? n1 : (N_NODES - 1);
  const float* row0 = evecs + (size_t)n0 * K_EIG + q * 8;
  const float* row1 = evecs + (size_t)n1 * K_EIG + q * 8;

  float4v acc[2][8];
#pragma unroll
  for (int a = 0; a < 2; a++)
#pragma unroll
    for (int b = 0; b < 8; b++) acc[a][b] = (float4v)0.0f;

  float4v c00 = *(const float4v*)(row0);
  float4v c01 = *(const float4v*)(row0 + 4);
  float4v c10 = *(const float4v*)(row1);
  float4v c11 = *(const float4v*)(row1 + 4);

#pragma unroll
  for (int ks = 0; ks < 8; ks++) {
    float4v nx00, nx01, nx10, nx11;
    if (ks < 7) {
      nx00 = *(const float4v*)(row0 + (ks + 1) * 32);
      nx01 = *(const float4v*)(row0 + (ks + 1) * 32 + 4);
      nx10 = *(const float4v*)(row1 + (ks + 1) * 32);
      nx11 = *(const float4v*)(row1 + (ks + 1) * 32 + 4);
    }
    short8 a0, a1;
    a0[0] = (short)bf16_bits(c00.x); a0[1] = (short)bf16_bits(c00.y);
    a0[2] = (short)bf16_bits(c00.z); a0[3] = (short)bf16_bits(c00.w);
    a0[4] = (short)bf16_bits(c01.x); a0[5] = (short)bf16_bits(c01.y);
    a0[6] = (short)bf16_bits(c01.z); a0[7] = (short)bf16_bits(c01.w);
    a1[0] = (short)bf16_bits(c10.x); a1[1] = (short)bf16_bits(c10.y);
    a1[2] = (short)bf16_bits(c10.z); a1[3] = (short)bf16_bits(c10.w);
    a1[4] = (short)bf16_bits(c11.x); a1[5] = (short)bf16_bits(c11.y);
    a1[6] = (short)bf16_bits(c11.z); a1[7] = (short)bf16_bits(c11.w);
#pragma unroll
    for (int ct = 0; ct < 8; ct++) {
      const short8 b = *(const short8*)&s_frag[(size_t)((ks * 8 + ct) * 64 + l) * 8];
      acc[0][ct] = __builtin_amdgcn_mfma_f32_16x16x32_bf16(a0, b, acc[0][ct], 0, 0, 0);
      acc[1][ct] = __builtin_amdgcn_mfma_f32_16x16x32_bf16(a1, b, acc[1][ct], 0, 0, 0);
    }
    c00 = nx00; c01 = nx01; c10 = nx10; c11 = nx11;
  }

#pragma unroll
  for (int rt = 0; rt < 2; rt++)
#pragma unroll
    for (int ct = 0; ct < 8; ct++)
#pragma unroll
      for (int r = 0; r < 4; r++) {
        const int n = rowbase + rt * 16 + q * 4 + r;
        if (n < N_NODES) out[(size_t)n * C_CH + ct * 16 + lc] = acc[rt][ct][r];
      }
}

// ---------------------------------------------------------------------------
extern "C" void kernel_launch(void* const* d_in, const int* in_sizes, int n_in,
                              void* d_out, int out_size, void* d_ws, size_t ws_size,
                              hipStream_t stream) {
  const float* x     = (const float*)d_in[0];   // [N, C]
  const float* evals = (const float*)d_in[1];   // [K]
  const float* evecs = (const float*)d_in[2];   // [N, K]
  const float* dt    = (const float*)d_in[3];   // [1]
  float* out = (float*)d_out;                   // [N, C] fp32

  // d_out doubles as split-K partial scratch: 4*313 tiles * 32KB = 41 MB <= 51.2 MB.
  float* partial = out;
  unsigned short* s_frag = (unsigned short*)d_ws;  // 64 KB bf16, fragment-ordered

  dim3 g1(NCHUNK, 4);
  gemm1_kernel<<<g1, 256, 0, stream>>>(x, evecs, partial);
  reduce_kernel<<<512, 256, 0, stream>>>(partial, evals, dt, s_frag);
  gemm2_kernel<<<G2_BLOCKS, 256, 0, stream>>>(evecs, s_frag, out);
}

// Round 2
// 245.761 us; speedup vs baseline: 1.1073x; 1.0777x over previous
//
#include <hip/hip_runtime.h>

#define N_NODES 100000
#define K_EIG   256
#define C_CH    128
#define BN      384              // rows per split-K chunk
#define NITER   6                // BN/64
#define NCHUNK  261              // ceil(N_NODES / BN); 261*384 = 100224
#define PART_TILE (128*64)       // floats per partial tile (4*261 tiles * 32KB = 33.4 MB <= d_out)
#define G2_BLOCKS 782            // ceil(N_NODES / 128)

typedef __attribute__((ext_vector_type(8))) short         short8;
typedef __attribute__((ext_vector_type(4))) float         float4v;
typedef __attribute__((ext_vector_type(2))) unsigned int  uint2v;

// fp32 -> bf16 bits with round-to-nearest-even
__device__ __forceinline__ unsigned int bf16_bits(float f) {
  union { float f; unsigned int u; } v; v.f = f;
  unsigned int r = v.u + 0x7fffu + ((v.u >> 16) & 1u);
  return r >> 16;
}
__device__ __forceinline__ unsigned int pack2(float a, float b) {
  return bf16_bits(a) | (bf16_bits(b) << 16);
}

// XOR-swizzled dword index into a k-major LDS tile: row-stride 32 dw (64 bf16),
// group-of-4-dw XOR keeps b128 reads 16B-aligned AND spreads the k-strided
// staging writes across banks (padding can't do both: 16B alignment forces
// stride%4==0 which makes column writes single-bank).
__device__ __forceinline__ int swz(int row, int nd) {
  return row * 32 + (nd ^ (((row ^ (row >> 3)) & 7) << 2));
}

// ---------------------------------------------------------------------------
// GEMM1: split-K MFMA. Output 256x128 split into 4 tiles of 128k x 64c
// (blockIdx.y = kt*2+ctile), 261 chunks of 384 rows -> 1044 blocks ~= 1.02
// dispatch rounds at 4 blocks/CU (LDS 24KB, launch_bounds(256,4)).
// LDS tiles are K-MAJOR (transposed during staging in registers): fragment
// reads are ds_read_b128 and staging writes ds_write_b64 -- 24 DS instr per
// lane per iter vs 120 for the old n-major tile (the old per-element
// ds_read_u16 fragment assembly serialized the whole CU on the LDS pipe).
// ---------------------------------------------------------------------------
__global__ __launch_bounds__(256, 4) void gemm1_kernel(
    const float* __restrict__ x, const float* __restrict__ evecs,
    float* __restrict__ partial) {
  __shared__ __align__(16) unsigned int ev_t[128 * 32];  // [k][n] bf16, swizzled
  __shared__ __align__(16) unsigned int x_t [64 * 32];   // [c][n] bf16, swizzled

  const int tid   = threadIdx.x;
  const int chunk = blockIdx.x;            // 0..NCHUNK-1
  const int tp    = blockIdx.y;            // 0..3 : kt*2 + ctile
  const int kt    = tp >> 1;
  const int ctile = tp & 1;
  const int w  = tid >> 6;                 // wave 0..3 -> k rows [w*32, w*32+32)
  const int l  = tid & 63;
  const int q  = l >> 4;
  const int lc = l & 15;

  // staging mapping: thread owns 4 consecutive n-rows (r4) x 8 ev-k / 4 x-c (k8)
  const int r4 = tid >> 4;                 // 0..15
  const int k8 = tid & 15;                 // 0..15

  float4v acc[2][4];
#pragma unroll
  for (int a = 0; a < 2; a++)
#pragma unroll
    for (int b = 0; b < 4; b++) acc[a][b] = (float4v)0.0f;

  float4v evr[4][2], xr[4];

  auto load_tile = [&](int it) {
    const int nb = chunk * BN + it * 64 + r4 * 4;
#pragma unroll
    for (int r = 0; r < 4; r++) {
      const int n = nb + r;
      const bool ok = (n < N_NODES);
      const float* evp = evecs + (size_t)n * K_EIG + kt * 128 + k8 * 8;
      const float* xp  = x     + (size_t)n * C_CH  + ctile * 64 + k8 * 4;
      evr[r][0] = ok ? *(const float4v*)(evp)     : (float4v)0.0f;
      evr[r][1] = ok ? *(const float4v*)(evp + 4) : (float4v)0.0f;
      xr[r]     = ok ? *(const float4v*)(xp)      : (float4v)0.0f;
    }
  };

  load_tile(0);

  for (int ic = 0; ic < NITER; ic++) {
    // stage current registers into LDS, transposed to k-major (b64 writes)
#pragma unroll
    for (int j = 0; j < 8; j++) {
      const int k = k8 * 8 + j;
      const int d = swz(k, r4 * 2);
      uint2v v;
      v.x = pack2(evr[0][j >> 2][j & 3], evr[1][j >> 2][j & 3]);
      v.y = pack2(evr[2][j >> 2][j & 3], evr[3][j >> 2][j & 3]);
      *(uint2v*)&ev_t[d] = v;
    }
#pragma unroll
    for (int j = 0; j < 4; j++) {
      const int c = k8 * 4 + j;
      const int d = swz(c, r4 * 2);
      uint2v v;
      v.x = pack2(xr[0][j], xr[1][j]);
      v.y = pack2(xr[2][j], xr[3][j]);
      *(uint2v*)&x_t[d] = v;
    }
    __syncthreads();

    // issue next iteration's global loads now; they complete during compute
    if (ic + 1 < NITER) load_tile(ic + 1);

#pragma unroll
    for (int ks = 0; ks < 2; ks++) {
      const int nd0 = ks * 16 + q * 4;     // dword offset of the 8-n slice
      short8 afrag[2];
#pragma unroll
      for (int mt = 0; mt < 2; mt++) {
        const int m = w * 32 + mt * 16 + lc;
        afrag[mt] = *(const short8*)&ev_t[swz(m, nd0)];
      }
#pragma unroll
      for (int ct = 0; ct < 4; ct++) {
        const int c = ct * 16 + lc;
        const short8 b = *(const short8*)&x_t[swz(c, nd0)];
        acc[0][ct] = __builtin_amdgcn_mfma_f32_16x16x32_bf16(afrag[0], b, acc[0][ct], 0, 0, 0);
        acc[1][ct] = __builtin_amdgcn_mfma_f32_16x16x32_bf16(afrag[1], b, acc[1][ct], 0, 0, 0);
      }
    }
    __syncthreads();
  }

  // C/D layout: col = lane&15, row = (lane>>4)*4 + reg
  float* pb = partial + (size_t)(tp * NCHUNK + chunk) * PART_TILE;
#pragma unroll
  for (int mt = 0; mt < 2; mt++)
#pragma unroll
    for (int ct = 0; ct < 4; ct++)
#pragma unroll
      for (int r = 0; r < 4; r++) {
        const int m = w * 32 + mt * 16 + q * 4 + r;
        const int c = ct * 16 + lc;
        pb[m * 64 + c] = acc[mt][ct][r];
      }
}

// ---------------------------------------------------------------------------
// Reduce partials, apply exp(-lambda*t), emit bf16 s pre-shuffled into MFMA
// B-fragment order: idx = (((k/32)*8 + c/16)*64 + ((k%32)/8)*16 + (c%16))*8 + k%8
// Partial layout: partial[(tp*NCHUNK + chunk)*8192 + m*64 + cc],
//   k = (tp>>1)*128 + m, c = (tp&1)*64 + cc
// ---------------------------------------------------------------------------
__global__ __launch_bounds__(256) void reduce_kernel(
    const float* __restrict__ partial, const float* __restrict__ evals,
    const float* __restrict__ dt, unsigned short* __restrict__ s_frag) {
  __shared__ float red[256];
  const int t  = threadIdx.x;
  const int o  = blockIdx.x * 64 + (t & 63);   // 0..32767
  const int p  = t >> 6;
  const int tp = o >> 13;                      // 0..3
  const int e  = o & 8191;                     // elem within tile
  const float* base = partial + (size_t)tp * NCHUNK * PART_TILE + e;
  float a0 = 0.f, a1 = 0.f, a2 = 0.f, a3 = 0.f;
  int ch = p;
  for (; ch + 12 < NCHUNK; ch += 16) {
    a0 += base[(size_t)(ch     ) * PART_TILE];
    a1 += base[(size_t)(ch +  4) * PART_TILE];
    a2 += base[(size_t)(ch +  8) * PART_TILE];
    a3 += base[(size_t)(ch + 12) * PART_TILE];
  }
  for (; ch < NCHUNK; ch += 4) a0 += base[(size_t)ch * PART_TILE];
  red[t] = (a0 + a1) + (a2 + a3);
  __syncthreads();
  if (t < 64) {
    const float tot = red[t] + red[t + 64] + red[t + 128] + red[t + 192];
    const int oo = blockIdx.x * 64 + t;
    const int tp2 = oo >> 13;
    const int e2  = oo & 8191;
    const int k = (tp2 >> 1) * 128 + (e2 >> 6);
    const int c = (tp2 & 1) * 64 + (e2 & 63);
    const float tv   = fmaxf(dt[0], 1e-8f);
    const float coef = expf(-evals[k] * tv);
    const float v = tot * coef;
    const int idx = ((((k >> 5) * 8 + (c >> 4)) * 64) + ((k & 31) >> 3) * 16 + (c & 15)) * 8 + (k & 7);
    s_frag[idx] = (unsigned short)bf16_bits(v);
  }
}

// ---------------------------------------------------------------------------
// GEMM2: out[n][c] = sum_k evecs[n][k] * s[k][c]
// No LDS at all: B-fragments stream from the fragment-ordered 64KB s buffer
// (L2-resident, lane-contiguous 16B reads); A rows come straight from global
// with explicit ks+1 register prefetch.
// ---------------------------------------------------------------------------
__global__ __launch_bounds__(256, 3) void gemm2_kernel(
    const float* __restrict__ evecs, const unsigned short* __restrict__ s_frag,
    float* __restrict__ out) {
  const int tid = threadIdx.x;
  const int w  = tid >> 6, l = tid & 63, q = l >> 4, lc = l & 15;
  const int rowbase = blockIdx.x * 128 + w * 32;

  int n0 = rowbase + lc;        n0 = (n0 < N_NODES) ? n0 : (N_NODES - 1);
  int n1 = rowbase + 16 + lc;   n1 = (n1 < N_NODES) ? n1 : (N_NODES - 1);
  const float* row0 = evecs + (size_t)n0 * K_EIG + q * 8;
  const float* row1 = evecs + (size_t)n1 * K_EIG + q * 8;

  float4v acc[2][8];
#pragma unroll
  for (int a = 0; a < 2; a++)
#pragma unroll
    for (int b = 0; b < 8; b++) acc[a][b] = (float4v)0.0f;

  float4v c00 = *(const float4v*)(row0);
  float4v c01 = *(const float4v*)(row0 + 4);
  float4v c10 = *(const float4v*)(row1);
  float4v c11 = *(const float4v*)(row1 + 4);

#pragma unroll
  for (int ks = 0; ks < 8; ks++) {
    float4v nx00, nx01, nx10, nx11;
    if (ks < 7) {
      nx00 = *(const float4v*)(row0 + (ks + 1) * 32);
      nx01 = *(const float4v*)(row0 + (ks + 1) * 32 + 4);
      nx10 = *(const float4v*)(row1 + (ks + 1) * 32);
      nx11 = *(const float4v*)(row1 + (ks + 1) * 32 + 4);
    }
    short8 a0, a1;
    a0[0] = (short)bf16_bits(c00.x); a0[1] = (short)bf16_bits(c00.y);
    a0[2] = (short)bf16_bits(c00.z); a0[3] = (short)bf16_bits(c00.w);
    a0[4] = (short)bf16_bits(c01.x); a0[5] = (short)bf16_bits(c01.y);
    a0[6] = (short)bf16_bits(c01.z); a0[7] = (short)bf16_bits(c01.w);
    a1[0] = (short)bf16_bits(c10.x); a1[1] = (short)bf16_bits(c10.y);
    a1[2] = (short)bf16_bits(c10.z); a1[3] = (short)bf16_bits(c10.w);
    a1[4] = (short)bf16_bits(c11.x); a1[5] = (short)bf16_bits(c11.y);
    a1[6] = (short)bf16_bits(c11.z); a1[7] = (short)bf16_bits(c11.w);
#pragma unroll
    for (int ct = 0; ct < 8; ct++) {
      const short8 b = *(const short8*)&s_frag[(size_t)((ks * 8 + ct) * 64 + l) * 8];
      acc[0][ct] = __builtin_amdgcn_mfma_f32_16x16x32_bf16(a0, b, acc[0][ct], 0, 0, 0);
      acc[1][ct] = __builtin_amdgcn_mfma_f32_16x16x32_bf16(a1, b, acc[1][ct], 0, 0, 0);
    }
    c00 = nx00; c01 = nx01; c10 = nx10; c11 = nx11;
  }

#pragma unroll
  for (int rt = 0; rt < 2; rt++)
#pragma unroll
    for (int ct = 0; ct < 8; ct++)
#pragma unroll
      for (int r = 0; r < 4; r++) {
        const int n = rowbase + rt * 16 + q * 4 + r;
        if (n < N_NODES) out[(size_t)n * C_CH + ct * 16 + lc] = acc[rt][ct][r];
      }
}

// ---------------------------------------------------------------------------
extern "C" void kernel_launch(void* const* d_in, const int* in_sizes, int n_in,
                              void* d_out, int out_size, void* d_ws, size_t ws_size,
                              hipStream_t stream) {
  const float* x     = (const float*)d_in[0];   // [N, C]
  const float* evals = (const float*)d_in[1];   // [K]
  const float* evecs = (const float*)d_in[2];   // [N, K]
  const float* dt    = (const float*)d_in[3];   // [1]
  float* out = (float*)d_out;                   // [N, C] fp32

  // d_out doubles as split-K partial scratch: 4*261 tiles * 32KB = 33.4 MB <= 51.2 MB.
  float* partial = out;
  unsigned short* s_frag = (unsigned short*)d_ws;  // 64 KB bf16, fragment-ordered

  dim3 g1(NCHUNK, 4);
  gemm1_kernel<<<g1, 256, 0, stream>>>(x, evecs, partial);
  reduce_kernel<<<512, 256, 0, stream>>>(partial, evals, dt, s_frag);
  gemm2_kernel<<<G2_BLOCKS, 256, 0, stream>>>(evecs, s_frag, out);
}